// Round 1
// baseline (10047.430 us; speedup 1.0000x reference)
//
#include <hip/hip_runtime.h>
#include <cstdint>
#include <cstddef>

#define NNODES 50000
#define NEDGES 800000
#define DF 64
#define HM 256
#define HU 256
#define KM 192   // 3*D  (msg MLP input dim)
#define KU 128   // 2*D  (upd MLP input dim)

// ---------------- message kernel ----------------
// 16 edges per block, 256 threads.
// thread t: edge eidx = t>>4, unit-group c = t&15 (owns 16 consecutive hidden units c*16..c*16+15)
__global__ __launch_bounds__(256, 4)
void msg_kernel(const float* __restrict__ h, const float* __restrict__ efeat,
                const int* __restrict__ snd, const int* __restrict__ rcv,
                const float* __restrict__ W1, const float* __restrict__ b1,
                const float* __restrict__ W2, const float* __restrict__ b2,
                float* __restrict__ agg)
{
    __shared__ float s_in[16][KM + 1];    // stride 193 -> bank = (eidx + k) % 32, conflict-free broadcast
    __shared__ float s_hid[16][HM + 1];   // stride 257 -> same property
    __shared__ int s_snd[16];
    __shared__ int s_rcv[16];

    const int t  = threadIdx.x;
    const int e0 = blockIdx.x * 16;

    if (t < 16)            s_snd[t]      = snd[e0 + t];
    else if (t < 32)       s_rcv[t - 16] = rcv[e0 + t - 16];
    __syncthreads();

    // stage m_in = concat(e, h[snd], h[rcv]) : 16 x 192 floats
    for (int i = t; i < 16 * KM; i += 256) {
        const int ee = i / KM;
        const int k  = i - ee * KM;
        float v;
        if (k < DF)            v = efeat[(size_t)(e0 + ee) * DF + k];
        else if (k < 2 * DF)   v = h[(size_t)s_snd[ee] * DF + (k - DF)];
        else                   v = h[(size_t)s_rcv[ee] * DF + (k - 2 * DF)];
        s_in[ee][k] = v;
    }
    __syncthreads();

    const int eidx = t >> 4;
    const int c    = t & 15;

    // ---- layer 1: hidden[c*16 .. c*16+15] ----
    float acc[16];
    {
        const float4* b1v = reinterpret_cast<const float4*>(b1 + c * 16);
        #pragma unroll
        for (int q = 0; q < 4; ++q) {
            const float4 bv = b1v[q];
            acc[4*q+0] = bv.x; acc[4*q+1] = bv.y; acc[4*q+2] = bv.z; acc[4*q+3] = bv.w;
        }
    }
    for (int k = 0; k < KM; ++k) {
        const float x = s_in[eidx][k];
        const float4* wr = reinterpret_cast<const float4*>(W1 + (size_t)k * HM + c * 16);
        #pragma unroll
        for (int q = 0; q < 4; ++q) {
            const float4 w = wr[q];
            acc[4*q+0] += x * w.x;
            acc[4*q+1] += x * w.y;
            acc[4*q+2] += x * w.z;
            acc[4*q+3] += x * w.w;
        }
    }
    #pragma unroll
    for (int j = 0; j < 16; ++j) s_hid[eidx][c * 16 + j] = fmaxf(acc[j], 0.f);
    __syncthreads();

    // ---- layer 2: outputs d = c*4 + q ----
    float o[4];
    {
        const float4 bv = reinterpret_cast<const float4*>(b2)[c];
        o[0] = bv.x; o[1] = bv.y; o[2] = bv.z; o[3] = bv.w;
    }
    for (int k = 0; k < HM; ++k) {
        const float xv = s_hid[eidx][k];
        const float4 w = reinterpret_cast<const float4*>(W2 + (size_t)k * DF)[c];
        o[0] += xv * w.x; o[1] += xv * w.y; o[2] += xv * w.z; o[3] += xv * w.w;
    }

    float* dst = agg + (size_t)s_rcv[eidx] * DF + c * 4;
    #pragma unroll
    for (int q = 0; q < 4; ++q) atomicAdd(dst + q, o[q]);
}

// ---------------- node-update kernel ----------------
// 16 nodes per block, 256 threads. Same decomposition.
// Safe when agg aliases out: each block stages its agg rows into LDS (and
// syncs) before any global write of those rows.
__global__ __launch_bounds__(256, 4)
void upd_kernel(const float* __restrict__ h, const float* __restrict__ agg,
                const float* __restrict__ W1, const float* __restrict__ b1,
                const float* __restrict__ W2, const float* __restrict__ b2,
                float* __restrict__ out)
{
    __shared__ float s_in[16][KU + 1];    // stride 129
    __shared__ float s_hid[16][HU + 1];   // stride 257

    const int t  = threadIdx.x;
    const int n0 = blockIdx.x * 16;

    // stage u_in = concat(h, agg) : 16 x 128 floats
    for (int i = t; i < 16 * KU; i += 256) {
        const int nn = i >> 7;
        const int k  = i & 127;
        const float v = (k < DF) ? h[(size_t)(n0 + nn) * DF + k]
                                 : agg[(size_t)(n0 + nn) * DF + (k - DF)];
        s_in[nn][k] = v;
    }
    __syncthreads();

    const int nidx = t >> 4;
    const int c    = t & 15;

    float acc[16];
    {
        const float4* b1v = reinterpret_cast<const float4*>(b1 + c * 16);
        #pragma unroll
        for (int q = 0; q < 4; ++q) {
            const float4 bv = b1v[q];
            acc[4*q+0] = bv.x; acc[4*q+1] = bv.y; acc[4*q+2] = bv.z; acc[4*q+3] = bv.w;
        }
    }
    for (int k = 0; k < KU; ++k) {
        const float x = s_in[nidx][k];
        const float4* wr = reinterpret_cast<const float4*>(W1 + (size_t)k * HU + c * 16);
        #pragma unroll
        for (int q = 0; q < 4; ++q) {
            const float4 w = wr[q];
            acc[4*q+0] += x * w.x;
            acc[4*q+1] += x * w.y;
            acc[4*q+2] += x * w.z;
            acc[4*q+3] += x * w.w;
        }
    }
    #pragma unroll
    for (int j = 0; j < 16; ++j) s_hid[nidx][c * 16 + j] = fmaxf(acc[j], 0.f);
    __syncthreads();

    float o[4];
    {
        const float4 bv = reinterpret_cast<const float4*>(b2)[c];
        o[0] = bv.x; o[1] = bv.y; o[2] = bv.z; o[3] = bv.w;
    }
    for (int k = 0; k < HU; ++k) {
        const float xv = s_hid[nidx][k];
        const float4 w = reinterpret_cast<const float4*>(W2 + (size_t)k * DF)[c];
        o[0] += xv * w.x; o[1] += xv * w.y; o[2] += xv * w.z; o[3] += xv * w.w;
    }

    // residual: out = h + dh
    const float4 hres = reinterpret_cast<const float4*>(h + (size_t)(n0 + nidx) * DF)[c];
    float4 r;
    r.x = o[0] + hres.x; r.y = o[1] + hres.y; r.z = o[2] + hres.z; r.w = o[3] + hres.w;
    reinterpret_cast<float4*>(out + (size_t)(n0 + nidx) * DF)[c] = r;
}

extern "C" void kernel_launch(void* const* d_in, const int* in_sizes, int n_in,
                              void* d_out, int out_size, void* d_ws, size_t ws_size,
                              hipStream_t stream)
{
    const float* h    = (const float*)d_in[0];
    const float* e    = (const float*)d_in[1];
    const int*   snd  = (const int*)d_in[2];
    const int*   rcv  = (const int*)d_in[3];
    const float* W_m1 = (const float*)d_in[4];
    const float* b_m1 = (const float*)d_in[5];
    const float* W_m2 = (const float*)d_in[6];
    const float* b_m2 = (const float*)d_in[7];
    const float* W_u1 = (const float*)d_in[8];
    const float* b_u1 = (const float*)d_in[9];
    const float* W_u2 = (const float*)d_in[10];
    const float* b_u2 = (const float*)d_in[11];
    float* out = (float*)d_out;

    const size_t agg_bytes = (size_t)NNODES * DF * sizeof(float);
    // agg in workspace; fall back to in-place d_out (upd_kernel stages its agg
    // rows into LDS before writing, so aliasing is safe).
    float* agg = (ws_size >= agg_bytes) ? (float*)d_ws : out;

    hipMemsetAsync(agg, 0, agg_bytes, stream);

    msg_kernel<<<NEDGES / 16, 256, 0, stream>>>(h, e, snd, rcv,
                                                W_m1, b_m1, W_m2, b_m2, agg);
    upd_kernel<<<NNODES / 16, 256, 0, stream>>>(h, agg,
                                                W_u1, b_u1, W_u2, b_u2, out);
}

// Round 2
// 585.694 us; speedup vs baseline: 17.1548x; 17.1548x over previous
//
#include <hip/hip_runtime.h>
#include <hip/hip_bf16.h>
#include <cstdint>
#include <cstddef>

#define NNODES 50000
#define NEDGES 800000
#define DF 64
#define KM 192      // msg MLP input dim (3*D)
#define KU 128      // upd MLP input dim (2*D)
#define SROW 264    // LDS row stride in bf16 elems (528 B = 33*16 -> aligned, bank-offset 4/row)

typedef __bf16 bf16_t;
typedef __bf16 bf16x8 __attribute__((ext_vector_type(8)));
typedef __bf16 bf16x4 __attribute__((ext_vector_type(4)));
typedef float  f32x4  __attribute__((ext_vector_type(4)));

// ---------------------------------------------------------------------------
// Weight packing: W[K][N] fp32 row-major  ->  Wp fragments bf16.
// Fragment (kblk, ct): lane l, elem j holds W[kblk*32 + (l>>4)*8 + j][ct*16 + (l&15)]
// Flat index: ((kblk*(N/16) + ct)*64 + l)*8 + j.
// Segments in wp: Wm1 (192x256) @0, Wm2 (256x64) @49152, Wu1 (128x256) @65536,
//                 Wu2 (256x64) @98304. Total 114688 elems.
// ---------------------------------------------------------------------------
__global__ void prep_kernel(const float* __restrict__ Wm1, const float* __restrict__ Wm2,
                            const float* __restrict__ Wu1, const float* __restrict__ Wu2,
                            bf16_t* __restrict__ wp)
{
    int idx = blockIdx.x * 256 + threadIdx.x;
    const float* src; int N; int off; int local;
    if (idx < 49152)       { src = Wm1; N = 256; off = 0;     local = idx; }
    else if (idx < 65536)  { src = Wm2; N = 64;  off = 49152; local = idx - 49152; }
    else if (idx < 98304)  { src = Wu1; N = 256; off = 65536; local = idx - 65536; }
    else if (idx < 114688) { src = Wu2; N = 64;  off = 98304; local = idx - 98304; }
    else return;
    int j    = local & 7;
    int l    = (local >> 3) & 63;
    int frag = local >> 9;
    int nct  = N >> 4;
    int kblk = frag / nct;
    int ct   = frag - kblk * nct;
    int k = kblk * 32 + (l >> 4) * 8 + j;
    int n = ct * 16 + (l & 15);
    wp[off + local] = (bf16_t)src[(size_t)k * N + n];
}

// ---------------------------------------------------------------------------
// Message kernel: 64 edges/block, 256 threads (4 waves).
// Wave w owns edges [w*16, w*16+16). Layer1: [16x192]@[192x256] via 6x16 MFMA.
// ReLU result written back into the wave's own LDS rows (in-order DS pipe, no
// cross-wave access after the gather barrier -> no further __syncthreads).
// Layer2: [16x256]@[256x64] via 8x4 MFMA. Scatter: fp32 atomics (+bias).
// ---------------------------------------------------------------------------
__global__ __launch_bounds__(256)
void msg_kernel(const float* __restrict__ h, const float* __restrict__ efeat,
                const int* __restrict__ snd, const int* __restrict__ rcv,
                const bf16_t* __restrict__ Wp1, const float* __restrict__ b1,
                const bf16_t* __restrict__ Wp2, const float* __restrict__ b2,
                float* __restrict__ agg)
{
    __shared__ bf16_t s_buf[64 * SROW];   // 33792 B: gather buf, then c1 (per-wave rows)
    __shared__ int s_snd[64];
    __shared__ int s_rcv[64];

    const int t  = threadIdx.x;
    const int e0 = blockIdx.x * 64;

    if (t < 64)       s_snd[t]      = snd[e0 + t];
    else if (t < 128) s_rcv[t - 64] = rcv[e0 + t - 64];
    __syncthreads();

    // gather m_in = [e | h_s | h_r] : 64 rows x 192 cols, float4 granularity
    #pragma unroll
    for (int it = 0; it < 12; ++it) {
        int i   = t + it * 256;        // < 3072 = 64*48
        int ee  = i / 48;
        int c4  = i - ee * 48;
        int col = c4 * 4;
        const float* srcp;
        if (col < DF)          srcp = efeat + (size_t)(e0 + ee) * DF + col;
        else if (col < 2 * DF) srcp = h + (size_t)s_snd[ee] * DF + (col - DF);
        else                   srcp = h + (size_t)s_rcv[ee] * DF + (col - 2 * DF);
        float4 v = *reinterpret_cast<const float4*>(srcp);
        bf16x4 bv;
        bv[0] = (bf16_t)v.x; bv[1] = (bf16_t)v.y; bv[2] = (bf16_t)v.z; bv[3] = (bf16_t)v.w;
        *reinterpret_cast<bf16x4*>(&s_buf[ee * SROW + col]) = bv;
    }
    __syncthreads();

    const int w = t >> 6;
    const int l = t & 63;
    const int q = l >> 4;
    const int r = l & 15;
    bf16_t* myrows = s_buf + (w * 16) * SROW;

    // ---- layer 1 ----
    f32x4 acc[16];
    #pragma unroll
    for (int ct = 0; ct < 16; ++ct) acc[ct] = (f32x4){0.f, 0.f, 0.f, 0.f};

    #pragma unroll
    for (int kb = 0; kb < 6; ++kb) {
        bf16x8 a = *reinterpret_cast<const bf16x8*>(&myrows[r * SROW + kb * 32 + q * 8]);
        #pragma unroll
        for (int ct = 0; ct < 16; ++ct) {
            bf16x8 b = *reinterpret_cast<const bf16x8*>(Wp1 + ((size_t)(kb * 16 + ct) * 64 + l) * 8);
            acc[ct] = __builtin_amdgcn_mfma_f32_16x16x32_bf16(a, b, acc[ct], 0, 0, 0);
        }
    }

    // bias + relu -> c1 into own LDS rows (row = local edge, col = hidden)
    #pragma unroll
    for (int ct = 0; ct < 16; ++ct) {
        float bias = b1[ct * 16 + r];
        #pragma unroll
        for (int j = 0; j < 4; ++j) {
            float v = fmaxf(acc[ct][j] + bias, 0.f);
            myrows[(q * 4 + j) * SROW + ct * 16 + r] = (bf16_t)v;
        }
    }

    // ---- layer 2 ----
    f32x4 acc2[4];
    #pragma unroll
    for (int ct = 0; ct < 4; ++ct) acc2[ct] = (f32x4){0.f, 0.f, 0.f, 0.f};

    #pragma unroll
    for (int kb = 0; kb < 8; ++kb) {
        bf16x8 a = *reinterpret_cast<const bf16x8*>(&myrows[r * SROW + kb * 32 + q * 8]);
        #pragma unroll
        for (int ct = 0; ct < 4; ++ct) {
            bf16x8 b = *reinterpret_cast<const bf16x8*>(Wp2 + ((size_t)(kb * 4 + ct) * 64 + l) * 8);
            acc2[ct] = __builtin_amdgcn_mfma_f32_16x16x32_bf16(a, b, acc2[ct], 0, 0, 0);
        }
    }

    // scatter (+bias) with fp32 atomics
    #pragma unroll
    for (int ct = 0; ct < 4; ++ct) {
        float bias = b2[ct * 16 + r];
        #pragma unroll
        for (int j = 0; j < 4; ++j) {
            int el = w * 16 + q * 4 + j;
            float v = acc2[ct][j] + bias;
            atomicAdd(agg + (size_t)s_rcv[el] * DF + ct * 16 + r, v);
        }
    }
}

// ---------------------------------------------------------------------------
// Node-update kernel: 64 nodes/block. Same template, K=128, residual store.
// Safe when agg aliases out: all reads of rows [n0,n0+64) happen before the
// barrier; stores to the same rows happen after.
// ---------------------------------------------------------------------------
__global__ __launch_bounds__(256)
void upd_kernel(const float* __restrict__ h, const float* __restrict__ agg,
                const bf16_t* __restrict__ Wp1, const float* __restrict__ b1,
                const bf16_t* __restrict__ Wp2, const float* __restrict__ b2,
                float* __restrict__ out)
{
    __shared__ bf16_t s_buf[64 * SROW];

    const int t  = threadIdx.x;
    const int n0 = blockIdx.x * 64;

    // gather u_in = [h | agg] : 64 rows x 128 cols
    #pragma unroll
    for (int it = 0; it < 8; ++it) {
        int i    = t + it * 256;       // < 2048 = 64*32
        int nn   = i >> 5;
        int col  = (i & 31) * 4;
        int node = n0 + nn;
        float4 v;
        if (node < NNODES) {
            const float* srcp = (col < DF) ? (h + (size_t)node * DF + col)
                                           : (agg + (size_t)node * DF + (col - DF));
            v = *reinterpret_cast<const float4*>(srcp);
        } else {
            v.x = 0.f; v.y = 0.f; v.z = 0.f; v.w = 0.f;
        }
        bf16x4 bv;
        bv[0] = (bf16_t)v.x; bv[1] = (bf16_t)v.y; bv[2] = (bf16_t)v.z; bv[3] = (bf16_t)v.w;
        *reinterpret_cast<bf16x4*>(&s_buf[nn * SROW + col]) = bv;
    }
    __syncthreads();

    const int w = t >> 6;
    const int l = t & 63;
    const int q = l >> 4;
    const int r = l & 15;
    bf16_t* myrows = s_buf + (w * 16) * SROW;

    f32x4 acc[16];
    #pragma unroll
    for (int ct = 0; ct < 16; ++ct) acc[ct] = (f32x4){0.f, 0.f, 0.f, 0.f};

    #pragma unroll
    for (int kb = 0; kb < 4; ++kb) {
        bf16x8 a = *reinterpret_cast<const bf16x8*>(&myrows[r * SROW + kb * 32 + q * 8]);
        #pragma unroll
        for (int ct = 0; ct < 16; ++ct) {
            bf16x8 b = *reinterpret_cast<const bf16x8*>(Wp1 + ((size_t)(kb * 16 + ct) * 64 + l) * 8);
            acc[ct] = __builtin_amdgcn_mfma_f32_16x16x32_bf16(a, b, acc[ct], 0, 0, 0);
        }
    }

    #pragma unroll
    for (int ct = 0; ct < 16; ++ct) {
        float bias = b1[ct * 16 + r];
        #pragma unroll
        for (int j = 0; j < 4; ++j) {
            float v = fmaxf(acc[ct][j] + bias, 0.f);
            myrows[(q * 4 + j) * SROW + ct * 16 + r] = (bf16_t)v;
        }
    }

    f32x4 acc2[4];
    #pragma unroll
    for (int ct = 0; ct < 4; ++ct) acc2[ct] = (f32x4){0.f, 0.f, 0.f, 0.f};

    #pragma unroll
    for (int kb = 0; kb < 8; ++kb) {
        bf16x8 a = *reinterpret_cast<const bf16x8*>(&myrows[r * SROW + kb * 32 + q * 8]);
        #pragma unroll
        for (int ct = 0; ct < 4; ++ct) {
            bf16x8 b = *reinterpret_cast<const bf16x8*>(Wp2 + ((size_t)(kb * 4 + ct) * 64 + l) * 8);
            acc2[ct] = __builtin_amdgcn_mfma_f32_16x16x32_bf16(a, b, acc2[ct], 0, 0, 0);
        }
    }

    // residual store: out = h + dh
    #pragma unroll
    for (int ct = 0; ct < 4; ++ct) {
        float bias = b2[ct * 16 + r];
        #pragma unroll
        for (int j = 0; j < 4; ++j) {
            int node = n0 + w * 16 + q * 4 + j;
            if (node < NNODES) {
                int col = ct * 16 + r;
                out[(size_t)node * DF + col] = h[(size_t)node * DF + col] + acc2[ct][j] + bias;
            }
        }
    }
}

extern "C" void kernel_launch(void* const* d_in, const int* in_sizes, int n_in,
                              void* d_out, int out_size, void* d_ws, size_t ws_size,
                              hipStream_t stream)
{
    const float* h    = (const float*)d_in[0];
    const float* e    = (const float*)d_in[1];
    const int*   snd  = (const int*)d_in[2];
    const int*   rcv  = (const int*)d_in[3];
    const float* W_m1 = (const float*)d_in[4];
    const float* b_m1 = (const float*)d_in[5];
    const float* W_m2 = (const float*)d_in[6];
    const float* b_m2 = (const float*)d_in[7];
    const float* W_u1 = (const float*)d_in[8];
    const float* b_u1 = (const float*)d_in[9];
    const float* W_u2 = (const float*)d_in[10];
    const float* b_u2 = (const float*)d_in[11];
    float* out = (float*)d_out;

    const size_t agg_bytes = (size_t)NNODES * DF * sizeof(float);   // 12.8 MB
    const size_t wp_elems  = 114688;
    const size_t wp_bytes  = wp_elems * sizeof(bf16_t);             // 229 KB

    float*  agg;
    bf16_t* wp;
    if (ws_size >= agg_bytes + wp_bytes) {
        agg = (float*)d_ws;
        wp  = (bf16_t*)((char*)d_ws + agg_bytes);
    } else {
        // fallback: alias agg onto out (upd reads its rows before writing them)
        agg = out;
        wp  = (bf16_t*)d_ws;
    }

    bf16_t* Wp_m1 = wp;
    bf16_t* Wp_m2 = wp + 49152;
    bf16_t* Wp_u1 = wp + 65536;
    bf16_t* Wp_u2 = wp + 98304;

    prep_kernel<<<448, 256, 0, stream>>>(W_m1, W_m2, W_u1, W_u2, wp);
    hipMemsetAsync(agg, 0, agg_bytes, stream);

    msg_kernel<<<NEDGES / 64, 256, 0, stream>>>(h, e, snd, rcv,
                                                Wp_m1, b_m1, Wp_m2, b_m2, agg);
    upd_kernel<<<(NNODES + 63) / 64, 256, 0, stream>>>(h, agg,
                                                       Wp_u1, b_u1, Wp_u2, b_u2, out);
}

// Round 3
// 313.114 us; speedup vs baseline: 32.0887x; 1.8705x over previous
//
#include <hip/hip_runtime.h>
#include <hip/hip_bf16.h>
#include <cstdint>
#include <cstddef>

#define NNODES 50000
#define NEDGES 800000
#define DF 64
#define KM 192      // msg MLP input dim (3*D)
#define KU 128      // upd MLP input dim (2*D)
#define SROW 264    // LDS row stride in bf16 elems (528 B -> 16B-aligned, ~2-way banks = free)

typedef __bf16 bf16_t;
typedef __bf16 bf16x8 __attribute__((ext_vector_type(8)));
typedef __bf16 bf16x4 __attribute__((ext_vector_type(4)));
typedef float  f32x4  __attribute__((ext_vector_type(4)));

// ---------------------------------------------------------------------------
// Weight packing: W[K][N] fp32 row-major  ->  bf16 MFMA B-fragments.
// Fragment (kblk, ct): lane l, elem j holds W[kblk*32 + (l>>4)*8 + j][ct*16 + (l&15)]
// Flat: ((kblk*(N/16) + ct)*64 + l)*8 + j.
// Segments: Wm1 @0 (49152), Wm2 @49152 (16384), Wu1 @65536 (32768), Wu2 @98304 (16384).
// ---------------------------------------------------------------------------
__global__ void prep_kernel(const float* __restrict__ Wm1, const float* __restrict__ Wm2,
                            const float* __restrict__ Wu1, const float* __restrict__ Wu2,
                            bf16_t* __restrict__ wp)
{
    int idx = blockIdx.x * 256 + threadIdx.x;
    const float* src; int N; int off; int local;
    if (idx < 49152)       { src = Wm1; N = 256; off = 0;     local = idx; }
    else if (idx < 65536)  { src = Wm2; N = 64;  off = 49152; local = idx - 49152; }
    else if (idx < 98304)  { src = Wu1; N = 256; off = 65536; local = idx - 65536; }
    else if (idx < 114688) { src = Wu2; N = 64;  off = 98304; local = idx - 98304; }
    else return;
    int j    = local & 7;
    int l    = (local >> 3) & 63;
    int frag = local >> 9;
    int nct  = N >> 4;
    int kblk = frag / nct;
    int ct   = frag - kblk * nct;
    int k = kblk * 32 + (l >> 4) * 8 + j;
    int n = ct * 16 + (l & 15);
    wp[off + local] = (bf16_t)src[(size_t)k * N + n];
}

// ---------------------------------------------------------------------------
// Message kernel: 64 edges/block, 4 waves. Waves split the N dimension:
//   layer1: wave w computes all 64 edges x cols [w*64, w*64+64)  (ct = 4w..4w+3)
//   layer2: wave w computes all 64 edges x cols [w*16, w*16+16)  (ct = w)
// Each B-frag feeds 4 row-fragment MFMAs -> 4x less B-load traffic than r2.
// c1 round-trips through s_buf (overwrites the input after a barrier).
// ---------------------------------------------------------------------------
__global__ __launch_bounds__(256, 4)
void msg_kernel(const float* __restrict__ h, const float* __restrict__ efeat,
                const int* __restrict__ snd, const int* __restrict__ rcv,
                const bf16_t* __restrict__ Wp1, const float* __restrict__ b1,
                const bf16_t* __restrict__ Wp2, const float* __restrict__ b2,
                float* __restrict__ agg)
{
    __shared__ bf16_t s_buf[64 * SROW];
    __shared__ int s_snd[64];
    __shared__ int s_rcv[64];

    const int t  = threadIdx.x;
    const int e0 = blockIdx.x * 64;

    if (t < 64)       s_snd[t]      = snd[e0 + t];
    else if (t < 128) s_rcv[t - 64] = rcv[e0 + t - 64];
    __syncthreads();

    // gather m_in = [e | h_s | h_r] : 64 rows x 192 cols
    #pragma unroll
    for (int it = 0; it < 12; ++it) {
        int i   = t + it * 256;        // < 3072 = 64*48
        int ee  = i / 48;
        int c4  = i - ee * 48;
        int col = c4 * 4;
        const float* srcp;
        if (col < DF)          srcp = efeat + (size_t)(e0 + ee) * DF + col;
        else if (col < 2 * DF) srcp = h + (size_t)s_snd[ee] * DF + (col - DF);
        else                   srcp = h + (size_t)s_rcv[ee] * DF + (col - 2 * DF);
        float4 v = *reinterpret_cast<const float4*>(srcp);
        bf16x4 bv;
        bv[0] = (bf16_t)v.x; bv[1] = (bf16_t)v.y; bv[2] = (bf16_t)v.z; bv[3] = (bf16_t)v.w;
        *reinterpret_cast<bf16x4*>(&s_buf[ee * SROW + col]) = bv;
    }
    __syncthreads();

    const int w = t >> 6;
    const int l = t & 63;
    const int q = l >> 4;
    const int r = l & 15;

    // ---- layer 1: M=64 (4 row-frags), N=64 per wave (4 ct) ----
    f32x4 acc[4][4];   // [g][am]
    #pragma unroll
    for (int g = 0; g < 4; ++g)
        #pragma unroll
        for (int am = 0; am < 4; ++am) acc[g][am] = (f32x4){0.f, 0.f, 0.f, 0.f};

    #pragma unroll
    for (int kb = 0; kb < 6; ++kb) {
        bf16x8 a[4];
        #pragma unroll
        for (int am = 0; am < 4; ++am)
            a[am] = *reinterpret_cast<const bf16x8*>(&s_buf[(am * 16 + r) * SROW + kb * 32 + q * 8]);
        #pragma unroll
        for (int g = 0; g < 4; ++g) {
            int ct = w * 4 + g;
            bf16x8 b = *reinterpret_cast<const bf16x8*>(Wp1 + ((size_t)(kb * 16 + ct) * 64 + l) * 8);
            #pragma unroll
            for (int am = 0; am < 4; ++am)
                acc[g][am] = __builtin_amdgcn_mfma_f32_16x16x32_bf16(a[am], b, acc[g][am], 0, 0, 0);
        }
    }
    __syncthreads();   // everyone done reading the input tile

    // bias + relu -> c1 into s_buf (row = edge, col = hidden unit)
    #pragma unroll
    for (int g = 0; g < 4; ++g) {
        int col = (w * 4 + g) * 16 + r;
        float bias = b1[col];
        #pragma unroll
        for (int am = 0; am < 4; ++am)
            #pragma unroll
            for (int j = 0; j < 4; ++j)
                s_buf[(am * 16 + q * 4 + j) * SROW + col] =
                    (bf16_t)fmaxf(acc[g][am][j] + bias, 0.f);
    }
    __syncthreads();   // c1 complete

    // ---- layer 2: M=64, N=16 per wave (ct = w) ----
    f32x4 acc2[4];
    #pragma unroll
    for (int am = 0; am < 4; ++am) acc2[am] = (f32x4){0.f, 0.f, 0.f, 0.f};

    #pragma unroll
    for (int kb = 0; kb < 8; ++kb) {
        bf16x8 a[4];
        #pragma unroll
        for (int am = 0; am < 4; ++am)
            a[am] = *reinterpret_cast<const bf16x8*>(&s_buf[(am * 16 + r) * SROW + kb * 32 + q * 8]);
        bf16x8 b = *reinterpret_cast<const bf16x8*>(Wp2 + ((size_t)(kb * 4 + w) * 64 + l) * 8);
        #pragma unroll
        for (int am = 0; am < 4; ++am)
            acc2[am] = __builtin_amdgcn_mfma_f32_16x16x32_bf16(a[am], b, acc2[am], 0, 0, 0);
    }

    // scatter (+bias): col = w*16 + r; lanes of equal q hit 64B-contiguous runs
    float bias2 = b2[w * 16 + r];
    #pragma unroll
    for (int am = 0; am < 4; ++am)
        #pragma unroll
        for (int j = 0; j < 4; ++j) {
            int el = am * 16 + q * 4 + j;
            atomicAdd(agg + (size_t)s_rcv[el] * DF + w * 16 + r, acc2[am][j] + bias2);
        }
}

// ---------------------------------------------------------------------------
// Node-update kernel: 64 nodes/block, same N-split template, K=128.
// Alias-safe when agg==out: all agg reads happen in the gather (before any
// store); stores come after the final barrier.
// ---------------------------------------------------------------------------
__global__ __launch_bounds__(256, 4)
void upd_kernel(const float* __restrict__ h, const float* __restrict__ agg,
                const bf16_t* __restrict__ Wp1, const float* __restrict__ b1,
                const bf16_t* __restrict__ Wp2, const float* __restrict__ b2,
                float* __restrict__ out)
{
    __shared__ bf16_t s_buf[64 * SROW];

    const int t  = threadIdx.x;
    const int n0 = blockIdx.x * 64;

    // gather u_in = [h | agg] : 64 rows x 128 cols
    #pragma unroll
    for (int it = 0; it < 8; ++it) {
        int i    = t + it * 256;       // < 2048 = 64*32
        int nn   = i >> 5;
        int col  = (i & 31) * 4;
        int node = n0 + nn;
        float4 v;
        if (node < NNODES) {
            const float* srcp = (col < DF) ? (h + (size_t)node * DF + col)
                                           : (agg + (size_t)node * DF + (col - DF));
            v = *reinterpret_cast<const float4*>(srcp);
        } else {
            v.x = 0.f; v.y = 0.f; v.z = 0.f; v.w = 0.f;
        }
        bf16x4 bv;
        bv[0] = (bf16_t)v.x; bv[1] = (bf16_t)v.y; bv[2] = (bf16_t)v.z; bv[3] = (bf16_t)v.w;
        *reinterpret_cast<bf16x4*>(&s_buf[nn * SROW + col]) = bv;
    }
    __syncthreads();

    const int w = t >> 6;
    const int l = t & 63;
    const int q = l >> 4;
    const int r = l & 15;

    f32x4 acc[4][4];
    #pragma unroll
    for (int g = 0; g < 4; ++g)
        #pragma unroll
        for (int am = 0; am < 4; ++am) acc[g][am] = (f32x4){0.f, 0.f, 0.f, 0.f};

    #pragma unroll
    for (int kb = 0; kb < 4; ++kb) {
        bf16x8 a[4];
        #pragma unroll
        for (int am = 0; am < 4; ++am)
            a[am] = *reinterpret_cast<const bf16x8*>(&s_buf[(am * 16 + r) * SROW + kb * 32 + q * 8]);
        #pragma unroll
        for (int g = 0; g < 4; ++g) {
            int ct = w * 4 + g;
            bf16x8 b = *reinterpret_cast<const bf16x8*>(Wp1 + ((size_t)(kb * 16 + ct) * 64 + l) * 8);
            #pragma unroll
            for (int am = 0; am < 4; ++am)
                acc[g][am] = __builtin_amdgcn_mfma_f32_16x16x32_bf16(a[am], b, acc[g][am], 0, 0, 0);
        }
    }
    __syncthreads();

    #pragma unroll
    for (int g = 0; g < 4; ++g) {
        int col = (w * 4 + g) * 16 + r;
        float bias = b1[col];
        #pragma unroll
        for (int am = 0; am < 4; ++am)
            #pragma unroll
            for (int j = 0; j < 4; ++j)
                s_buf[(am * 16 + q * 4 + j) * SROW + col] =
                    (bf16_t)fmaxf(acc[g][am][j] + bias, 0.f);
    }
    __syncthreads();

    f32x4 acc2[4];
    #pragma unroll
    for (int am = 0; am < 4; ++am) acc2[am] = (f32x4){0.f, 0.f, 0.f, 0.f};

    #pragma unroll
    for (int kb = 0; kb < 8; ++kb) {
        bf16x8 a[4];
        #pragma unroll
        for (int am = 0; am < 4; ++am)
            a[am] = *reinterpret_cast<const bf16x8*>(&s_buf[(am * 16 + r) * SROW + kb * 32 + q * 8]);
        bf16x8 b = *reinterpret_cast<const bf16x8*>(Wp2 + ((size_t)(kb * 4 + w) * 64 + l) * 8);
        #pragma unroll
        for (int am = 0; am < 4; ++am)
            acc2[am] = __builtin_amdgcn_mfma_f32_16x16x32_bf16(a[am], b, acc2[am], 0, 0, 0);
    }

    // residual store: out = h + dh  (col = w*16 + r)
    float bias2 = b2[w * 16 + r];
    #pragma unroll
    for (int am = 0; am < 4; ++am)
        #pragma unroll
        for (int j = 0; j < 4; ++j) {
            int node = n0 + am * 16 + q * 4 + j;
            if (node < NNODES) {
                int col = w * 16 + r;
                out[(size_t)node * DF + col] =
                    h[(size_t)node * DF + col] + acc2[am][j] + bias2;
            }
        }
}

extern "C" void kernel_launch(void* const* d_in, const int* in_sizes, int n_in,
                              void* d_out, int out_size, void* d_ws, size_t ws_size,
                              hipStream_t stream)
{
    const float* h    = (const float*)d_in[0];
    const float* e    = (const float*)d_in[1];
    const int*   snd  = (const int*)d_in[2];
    const int*   rcv  = (const int*)d_in[3];
    const float* W_m1 = (const float*)d_in[4];
    const float* b_m1 = (const float*)d_in[5];
    const float* W_m2 = (const float*)d_in[6];
    const float* b_m2 = (const float*)d_in[7];
    const float* W_u1 = (const float*)d_in[8];
    const float* b_u1 = (const float*)d_in[9];
    const float* W_u2 = (const float*)d_in[10];
    const float* b_u2 = (const float*)d_in[11];
    float* out = (float*)d_out;

    const size_t agg_bytes = (size_t)NNODES * DF * sizeof(float);   // 12.8 MB
    const size_t wp_bytes  = 114688 * sizeof(bf16_t);               // 229 KB

    float*  agg;
    bf16_t* wp;
    if (ws_size >= agg_bytes + wp_bytes) {
        agg = (float*)d_ws;
        wp  = (bf16_t*)((char*)d_ws + agg_bytes);
    } else {
        agg = out;               // alias-safe per upd_kernel structure
        wp  = (bf16_t*)d_ws;
    }

    bf16_t* Wp_m1 = wp;
    bf16_t* Wp_m2 = wp + 49152;
    bf16_t* Wp_u1 = wp + 65536;
    bf16_t* Wp_u2 = wp + 98304;

    prep_kernel<<<448, 256, 0, stream>>>(W_m1, W_m2, W_u1, W_u2, wp);
    hipMemsetAsync(agg, 0, agg_bytes, stream);

    msg_kernel<<<NEDGES / 64, 256, 0, stream>>>(h, e, snd, rcv,
                                                Wp_m1, b_m1, Wp_m2, b_m2, agg);
    upd_kernel<<<(NNODES + 63) / 64, 256, 0, stream>>>(h, agg,
                                                       Wp_u1, b_u1, Wp_u2, b_u2, out);
}